// Round 7
// baseline (49.689 us; speedup 1.0000x reference)
//
#include <hip/hip_runtime.h>

#define IN_CH 3
#define OUT_CH 32
#define IN_FEAT 27
#define NB 5
#define NG 8
#define HH 256
#define WW 256
#define NPIX (16 * HH * WW)

// Phi record: 24 fp16 payload, padded to 28 halves (56 B) in LDS for bank spread
#define RECE 24
#define RECP 28
#define TW 66                            // halo tile width (64 + 2)
#define TROWS 10                         // halo rows (8 + 2)
#define NREC (TROWS * TW)                // 660 records per block
#define WB_HALVES (9 * 2 * 64 * 8)       // 9216 halves = 18432 B
#define WS_NEEDED ((size_t)WB_HALVES * 2 + 16)

typedef __attribute__((ext_vector_type(8))) _Float16 half8;
typedef __attribute__((ext_vector_type(4))) float f32x4;
typedef __attribute__((ext_vector_type(4))) unsigned int u32x4;

// Reference-exact phi (Cox-de Boor) -- used by prep + fallback only
__device__ inline void kan_phi6(float xx, const float* g, const float* r1, const float* r2,
                                float* o6) {
    const float sig = 1.0f / (1.0f + __expf(-xx));
    o6[0] = xx * sig;
    float b0[7];
#pragma unroll
    for (int j = 0; j < 7; ++j) b0[j] = (xx >= g[j] && xx < g[j + 1]) ? 1.0f : 0.0f;
    float b1[6];
#pragma unroll
    for (int j = 0; j < 6; ++j)
        b1[j] = (xx - g[j]) * r1[j] * b0[j] + (g[j + 2] - xx) * r1[j + 1] * b0[j + 1];
#pragma unroll
    for (int j = 0; j < NB; ++j)
        o6[1 + j] = (xx - g[j]) * r2[j] * b1[j] + (g[j + 3] - xx) * r2[j + 1] * b1[j + 1];
}

__device__ inline void load_grid(const float* __restrict__ grid, float* g, float* r1, float* r2) {
#pragma unroll
    for (int j = 0; j < NG; ++j) g[j] = grid[j];
#pragma unroll
    for (int j = 0; j < NG - 1; ++j) r1[j] = 1.0f / (g[j + 1] - g[j]);
#pragma unroll
    for (int j = 0; j < NG - 2; ++j) r2[j] = 1.0f / (g[j + 2] - g[j]);
}

// ---------------------------------------------------------------------------
// Prep: weights -> exact B-fragment layout (fp16). wb[((tap*2+nt)*64+lane)*8+e]
// Thread 0 also writes {g0, invh} after wb (grid is uniform: h = 2/3).
// ---------------------------------------------------------------------------
__global__ void kan_prepW(const float* __restrict__ bw, const float* __restrict__ sw,
                          const float* __restrict__ ss, const float* __restrict__ grid,
                          _Float16* __restrict__ wb) {
    int t = blockIdx.x * 256 + threadIdx.x;
    if (t >= 9 * 2 * 64) return;

    if (t == 0) {
        float* gt = (float*)(wb + WB_HALVES);
        gt[0] = grid[0];
        gt[1] = 7.0f / (grid[7] - grid[0]);   // 1/h (uniform best fit)
    }

    const int lane = t & 63;
    const int nt = (t >> 6) & 1;
    const int tap = t >> 7;
    const int o = nt * 16 + (lane & 15);
    const int kbase = (lane >> 4) * 8;
    half8 v8 = {0, 0, 0, 0, 0, 0, 0, 0};
#pragma unroll
    for (int e = 0; e < 8; ++e) {
        int kk = kbase + e;
        float v = 0.0f;
        if (kk < 18) {
            int c = kk / 6, j = kk % 6;
            int f = c * 9 + tap;
            int of = o * IN_FEAT + f;
            v = (j == 0) ? bw[of] : sw[of * NB + (j - 1)] * ss[of];
        }
        v8[e] = (_Float16)v;
    }
    *(half8*)(wb + (size_t)t * 8) = v8;
}

// ---------------------------------------------------------------------------
// Fused kernel: block = 256 thr = 4 waves; tile = 64 wide x 8 rows = 512 pixels.
//  Phase 1: 660 halo records (10x66) -> LDS, closed-form uniform B-spline.
//  Phase 2: wave wid owns rows h0+2*wid..+1: per M-tile load 4 halo-rows x 3 dx
//           (12 ds_read_b128), 36 MFMA (2 rows x 9 taps x 2 N), direct stores.
// ---------------------------------------------------------------------------
__global__ __launch_bounds__(256) void kan_fused(const float* __restrict__ x,
                                                 const _Float16* __restrict__ wb,
                                                 float* __restrict__ out) {
    __shared__ _Float16 lPhi[NREC * RECP];   // 36960 B

    const int tid = threadIdx.x;
    const int bid = blockIdx.x;
    const int strip = bid & 3;
    const int rowg = (bid >> 2) & 31;
    const int b = bid >> 7;
    const int h0 = rowg * 8;
    const int w0 = strip * 64;

    const int lane = tid & 63;
    const int wid = tid >> 6;
    const int r = lane & 15;      // A row (pixel) / B col (channel) within tile
    const int gq = lane >> 4;     // k-group (0..3); gq==3 -> zero pad

    // ---- B-fragments: straight from global (L2-resident), once per thread ----
    half8 bf[18];
#pragma unroll
    for (int i = 0; i < 18; ++i)
        bf[i] = *(const half8*)(wb + ((size_t)(i * 64 + lane)) * 8);

    const float* gt = (const float*)(wb + WB_HALVES);
    const float g0 = gt[0];
    const float invh = gt[1];

    // ---- Phase 1: phi halo tile (closed-form uniform quadratic B-spline) ----
    for (int ri = tid; ri < NREC; ri += 256) {
        const int dyR = ri / TW;             // 0..9
        const int wxR = ri - dyR * TW - 1;   // -1..64
        const int hy = h0 + dyR - 1;
        const int wx = w0 + wxR;
        const bool vld = ((unsigned)hy < HH) & ((unsigned)wx < WW);

        _Float16 rec[RECE];
#pragma unroll
        for (int c = 0; c < IN_CH; ++c) {
            const float xx = vld ? x[((b * IN_CH + c) << 16) + (hy << 8) + wx] : 0.0f;
            // silu
            const float sig = 1.0f / (1.0f + __expf(-xx));
            rec[c * 6] = (_Float16)(xx * sig);
            // closed-form bases: u = (x-g0)/h, 3 nonzero weights at i0-2..i0
            const float u = (xx - g0) * invh;
            const float fi = floorf(u);
            const int i0 = (int)fi;
            const float t = u - fi;
            const float om = 1.0f - t;
            float wA = 0.5f * om * om;          // slot i0-2
            float wC = 0.5f * t * t;            // slot i0
            float wB = 1.0f - wA - wC;          // slot i0-1
            const bool valid = (fi >= 0.0f) & (i0 <= 6);
            wA = valid ? wA : 0.0f;
            wB = valid ? wB : 0.0f;
            wC = valid ? wC : 0.0f;
#pragma unroll
            for (int j = 0; j < NB; ++j) {
                float v = (j == i0 - 2) ? wA : ((j == i0 - 1) ? wB : ((j == i0) ? wC : 0.0f));
                rec[c * 6 + 1 + j] = (_Float16)v;
            }
        }
#pragma unroll
        for (int j = 18; j < RECE; ++j) rec[j] = (_Float16)0.0f;

        half8* dst = (half8*)(lPhi + ri * RECP);
        dst[0] = *(half8*)(rec + 0);
        dst[1] = *(half8*)(rec + 8);
        dst[2] = *(half8*)(rec + 16);
    }
    __syncthreads();

    // ---- Phase 2: wave handles rows row0, row0+1; 4 M-tiles along the row ----
    const int row0 = wid * 2;
    const int hr0 = h0 + row0;
#pragma unroll
    for (int m = 0; m < 4; ++m) {
        half8 haf[4][3];
#pragma unroll
        for (int hr = 0; hr < 4; ++hr) {
#pragma unroll
            for (int dx = 0; dx < 3; ++dx) {
                const int ridx = (row0 + hr) * TW + m * 16 + r + dx;
                half8 v = {0, 0, 0, 0, 0, 0, 0, 0};
                if (gq < 3) v = *(const half8*)(lPhi + ridx * RECP + gq * 8);
                haf[hr][dx] = v;
            }
        }

        f32x4 a00 = {0.f, 0.f, 0.f, 0.f};
        f32x4 a01 = {0.f, 0.f, 0.f, 0.f};
        f32x4 a10 = {0.f, 0.f, 0.f, 0.f};
        f32x4 a11 = {0.f, 0.f, 0.f, 0.f};
#pragma unroll
        for (int dy = 0; dy < 3; ++dy) {
#pragma unroll
            for (int dx = 0; dx < 3; ++dx) {
                const int tap = dy * 3 + dx;
                a00 = __builtin_amdgcn_mfma_f32_16x16x32_f16(haf[dy][dx],     bf[tap * 2 + 0], a00, 0, 0, 0);
                a01 = __builtin_amdgcn_mfma_f32_16x16x32_f16(haf[dy][dx],     bf[tap * 2 + 1], a01, 0, 0, 0);
                a10 = __builtin_amdgcn_mfma_f32_16x16x32_f16(haf[dy + 1][dx], bf[tap * 2 + 0], a10, 0, 0, 0);
                a11 = __builtin_amdgcn_mfma_f32_16x16x32_f16(haf[dy + 1][dx], bf[tap * 2 + 1], a11, 0, 0, 0);
            }
        }

        // Direct stores: lane = 4 consecutive-w pixels for channel r / r+16
        const int wcol = w0 + m * 16 + gq * 4;
        float* p00 = out + ((size_t)(b * OUT_CH + r) << 16)      + (hr0 << 8)       + wcol;
        float* p01 = out + ((size_t)(b * OUT_CH + 16 + r) << 16) + (hr0 << 8)       + wcol;
        float* p10 = out + ((size_t)(b * OUT_CH + r) << 16)      + ((hr0 + 1) << 8) + wcol;
        float* p11 = out + ((size_t)(b * OUT_CH + 16 + r) << 16) + ((hr0 + 1) << 8) + wcol;
        *(f32x4*)p00 = a00;
        *(f32x4*)p01 = a01;
        *(f32x4*)p10 = a10;
        *(f32x4*)p11 = a11;
    }
}

// ===========================================================================
// Fallback (round-1 fp32 path) if ws_size is too small for wb
// ===========================================================================
__global__ void kan_combine_weights(const float* __restrict__ bw,
                                    const float* __restrict__ sw,
                                    const float* __restrict__ ss,
                                    float* __restrict__ wc) {
    int idx = blockIdx.x * blockDim.x + threadIdx.x;
    if (idx >= IN_FEAT * 6 * OUT_CH) return;
    int o = idx & 31;
    int j = (idx >> 5) % 6;
    int f = idx / (6 * 32);
    float v;
    if (j == 0) v = bw[o * IN_FEAT + f];
    else        v = sw[(o * IN_FEAT + f) * NB + (j - 1)] * ss[o * IN_FEAT + f];
    wc[idx] = v;
}

__global__ __launch_bounds__(256) void kan_main(const float* __restrict__ x,
                                                const float* __restrict__ grid,
                                                const float* __restrict__ wc,
                                                float* __restrict__ out) {
    const int p = blockIdx.x * blockDim.x + threadIdx.x;
    const int w = p & (WW - 1);
    const int h = (p >> 8) & (HH - 1);
    const int b = p >> 16;
    float g[NG], r1[NG - 1], r2[NG - 2];
    load_grid(grid, g, r1, r2);
    float acc[OUT_CH];
#pragma unroll
    for (int o = 0; o < OUT_CH; ++o) acc[o] = 0.0f;
    const float* xb = x + b * (IN_CH * HH * WW);
    for (int c = 0; c < IN_CH; ++c) {
        const float* xc = xb + c * (HH * WW);
#pragma unroll
        for (int dy = 0; dy < 3; ++dy) {
            const int hy = h + dy - 1;
            const bool vy = (hy >= 0) && (hy < HH);
#pragma unroll
            for (int dx = 0; dx < 3; ++dx) {
                const int wx = w + dx - 1;
                const bool vld = vy && (wx >= 0) && (wx < WW);
                const float xx = vld ? xc[hy * WW + wx] : 0.0f;
                float o6[6];
                kan_phi6(xx, g, r1, r2, o6);
                const float* wf = wc + (c * 9 + dy * 3 + dx) * (6 * OUT_CH);
#pragma unroll
                for (int jj = 0; jj < 6; ++jj) {
                    const float* wj = wf + jj * OUT_CH;
#pragma unroll
                    for (int o = 0; o < OUT_CH; ++o) acc[o] += o6[jj] * wj[o];
                }
            }
        }
    }
    float* ob = out + (size_t)b * (OUT_CH * HH * WW) + h * WW + w;
#pragma unroll
    for (int o = 0; o < OUT_CH; ++o) ob[o * (HH * WW)] = acc[o];
}

// ===========================================================================
extern "C" void kernel_launch(void* const* d_in, const int* in_sizes, int n_in,
                              void* d_out, int out_size, void* d_ws, size_t ws_size,
                              hipStream_t stream) {
    const float* x    = (const float*)d_in[0];
    const float* bw   = (const float*)d_in[1];
    const float* sw   = (const float*)d_in[2];
    const float* ss   = (const float*)d_in[3];
    const float* grid = (const float*)d_in[4];
    float* out = (float*)d_out;

    if (ws_size >= WS_NEEDED) {
        _Float16* wb = (_Float16*)d_ws;
        kan_prepW<<<(9 * 2 * 64 + 255) / 256, 256, 0, stream>>>(bw, sw, ss, grid, wb);
        kan_fused<<<NPIX / 512, 256, 0, stream>>>(x, wb, out);
    } else {
        float* wc = (float*)d_ws;
        kan_combine_weights<<<(IN_FEAT * 6 * OUT_CH + 255) / 256, 256, 0, stream>>>(bw, sw, ss, wc);
        kan_main<<<NPIX / 256, 256, 0, stream>>>(x, grid, wc, out);
    }
}